// Round 6
// baseline (283.756 us; speedup 1.0000x reference)
//
#include <hip/hip_runtime.h>
#include <math.h>

#define NB    4
#define NSEQ  2048
#define DMODEL 512
#define NH    8
#define HDIM  64
#define STR   72   // P-slot LDS row stride (bf16 units): 144B rows, 16B-aligned

typedef __attribute__((ext_vector_type(8))) short short8;
typedef __attribute__((ext_vector_type(4))) float f32x4;
#define MFMA16 __builtin_amdgcn_mfma_f32_16x16x32_bf16

__device__ __forceinline__ unsigned short f2bf(float f) {
    union { float f; unsigned int u; } v; v.f = f;
    unsigned int u = v.u;
    unsigned int r = (u + 0x7FFFu + ((u >> 16) & 1u)) >> 16;   // RNE
    return (unsigned short)r;
}
__device__ __forceinline__ float bf2f(unsigned short h) {
    union { unsigned int u; float f; } v; v.u = ((unsigned int)h) << 16;
    return v.f;
}
// AND a P-fragment (8 bf16, keys j=0..7) with 8 adjacency bits
__device__ __forceinline__ short8 andmask8(short8 p, unsigned bits) {
    union { short8 s; uint4 u; } x; x.s = p;
    x.u.x &= ((bits &   1u) ? 0xFFFFu : 0u) | ((bits &   2u) ? 0xFFFF0000u : 0u);
    x.u.y &= ((bits &   4u) ? 0xFFFFu : 0u) | ((bits &   8u) ? 0xFFFF0000u : 0u);
    x.u.z &= ((bits &  16u) ? 0xFFFFu : 0u) | ((bits &  32u) ? 0xFFFF0000u : 0u);
    x.u.w &= ((bits &  64u) ? 0xFFFFu : 0u) | ((bits & 128u) ? 0xFFFF0000u : 0u);
    return x.s;
}
__device__ __forceinline__ void async16(void* lds, const void* g) {
    __builtin_amdgcn_global_load_lds(
        (const __attribute__((address_space(1))) unsigned int*)g,
        (__attribute__((address_space(3))) unsigned int*)lds, 16, 0, 0);
}

// ---------------------------------------------------------------------------
// Mask precompute: Mb[kt*2048 + q] = 64-bit word, bit i = adj[q][kt*64+i] > 0.5
// ---------------------------------------------------------------------------
__global__ __launch_bounds__(256) void mask_kernel(const float* __restrict__ adj,
                                                   unsigned long long* __restrict__ Mb) {
    const int w    = blockIdx.x * 4 + (threadIdx.x >> 6);   // global wave id
    const int lane = threadIdx.x & 63;
    const int q  = w >> 5;          // 0..2047
    const int kt = w & 31;          // 0..31
    float a = adj[(size_t)q * NSEQ + kt * 64 + lane];
    unsigned long long m = __ballot(a > 0.5f);
    if (lane == 0) Mb[(size_t)kt * NSEQ + q] = m;
}

// ---------------------------------------------------------------------------
// Split x (fp32) -> xhi, xlo bf16
// ---------------------------------------------------------------------------
__global__ __launch_bounds__(256) void split_x_kernel(const float* __restrict__ x,
                                                      unsigned short* __restrict__ xhi,
                                                      unsigned short* __restrict__ xlo) {
    int gid = blockIdx.x * 256 + threadIdx.x;
    float4 a = ((const float4*)x)[gid];
    float f[4] = {a.x, a.y, a.z, a.w};
    ushort4 h4, l4;
    unsigned short hs[4], ls[4];
    #pragma unroll
    for (int j = 0; j < 4; ++j) {
        hs[j] = f2bf(f[j]);
        ls[j] = f2bf(f[j] - bf2f(hs[j]));
    }
    h4.x = hs[0]; h4.y = hs[1]; h4.z = hs[2]; h4.w = hs[3];
    l4.x = ls[0]; l4.y = ls[1]; l4.z = ls[2]; l4.w = ls[3];
    ((ushort4*)xhi)[gid] = h4;
    ((ushort4*)xlo)[gid] = l4;
}

// ---------------------------------------------------------------------------
// Transpose + split weights: W[k][n] fp32 -> Wt_hi/Wt_lo [mat][n][k] bf16.
// ---------------------------------------------------------------------------
__global__ __launch_bounds__(256) void split_wt_kernel(
    const float* __restrict__ Wq, const float* __restrict__ Wk,
    const float* __restrict__ Wv, const float* __restrict__ Wo,
    unsigned short* __restrict__ Wthi, unsigned short* __restrict__ Wtlo)
{
    __shared__ float tile[32][33];
    const int m = blockIdx.z;
    const float* W = (m == 0) ? Wq : (m == 1) ? Wk : (m == 2) ? Wv : Wo;
    const int k0 = blockIdx.x * 32, n0 = blockIdx.y * 32;
    const int tx = threadIdx.x & 31, ty = threadIdx.x >> 5;
    #pragma unroll
    for (int i = 0; i < 4; ++i)
        tile[ty * 4 + i][tx] = W[(size_t)(k0 + ty * 4 + i) * DMODEL + n0 + tx];
    __syncthreads();
    const size_t base = ((size_t)m * DMODEL) * DMODEL;
    #pragma unroll
    for (int i = 0; i < 4; ++i) {
        float f = tile[tx][ty * 4 + i];
        unsigned short hi = f2bf(f);
        unsigned short lo = f2bf(f - bf2f(hi));
        size_t idx = base + (size_t)(n0 + ty * 4 + i) * DMODEL + k0 + tx;
        Wthi[idx] = hi;
        Wtlo[idx] = lo;
    }
}

// ---------------------------------------------------------------------------
// Shared MFMA GEMM K-loop (hi/lo 3-term), 128x128 tile, BK=32, XOR-swizzled LDS.
// ---------------------------------------------------------------------------
__device__ __forceinline__ void gemm_k_loop(
    const unsigned short* __restrict__ Ah, const unsigned short* __restrict__ Al,
    const unsigned short* __restrict__ Bh, const unsigned short* __restrict__ Bl,
    char* smem, f32x4 acc[4][4])
{
    const int t    = threadIdx.x;
    const int lane = t & 63;
    const int wid  = t >> 6;
    const int quad = lane >> 4, l16 = lane & 15;
    const int wm   = wid >> 1,  wn  = wid & 1;

    unsigned short* As_h = (unsigned short*)(smem);
    unsigned short* As_l = (unsigned short*)(smem + 8192);
    unsigned short* Bs_h = (unsigned short*)(smem + 16384);
    unsigned short* Bs_l = (unsigned short*)(smem + 24576);

    const int ci0 = t, ci1 = 256 + t;
    const int r0 = ci0 >> 2, r1 = ci1 >> 2;
    const int c0 = (ci0 & 3) ^ ((r0 >> 1) & 3);
    const int c1 = (ci1 & 3) ^ ((r1 >> 1) & 3);
    const char* gAh = (const char*)Ah;  const char* gAl = (const char*)Al;
    const char* gBh = (const char*)Bh;  const char* gBl = (const char*)Bl;
    const int ca = quad ^ ((l16 >> 1) & 3);

    for (int k0 = 0; k0 < DMODEL; k0 += 32) {
        const int kb = k0 * 2;
        async16(As_h + ci0 * 8, gAh + r0 * 1024 + kb + c0 * 16);
        async16(As_h + ci1 * 8, gAh + r1 * 1024 + kb + c1 * 16);
        async16(As_l + ci0 * 8, gAl + r0 * 1024 + kb + c0 * 16);
        async16(As_l + ci1 * 8, gAl + r1 * 1024 + kb + c1 * 16);
        async16(Bs_h + ci0 * 8, gBh + r0 * 1024 + kb + c0 * 16);
        async16(Bs_h + ci1 * 8, gBh + r1 * 1024 + kb + c1 * 16);
        async16(Bs_l + ci0 * 8, gBl + r0 * 1024 + kb + c0 * 16);
        async16(Bs_l + ci1 * 8, gBl + r1 * 1024 + kb + c1 * 16);
        __syncthreads();

        short8 ah[4], al[4], bh[4], bl[4];
        #pragma unroll
        for (int i = 0; i < 4; ++i) {
            const int Ra = wm * 64 + i * 16 + l16;
            ah[i] = *(const short8*)(As_h + Ra * 32 + ca * 8);
            al[i] = *(const short8*)(As_l + Ra * 32 + ca * 8);
            const int Rb = wn * 64 + i * 16 + l16;
            bh[i] = *(const short8*)(Bs_h + Rb * 32 + ca * 8);
            bl[i] = *(const short8*)(Bs_l + Rb * 32 + ca * 8);
        }
        #pragma unroll
        for (int mi = 0; mi < 4; ++mi)
            #pragma unroll
            for (int ni = 0; ni < 4; ++ni) {
                acc[mi][ni] = MFMA16(ah[mi], bh[ni], acc[mi][ni], 0, 0, 0);
                acc[mi][ni] = MFMA16(al[mi], bh[ni], acc[mi][ni], 0, 0, 0);
                acc[mi][ni] = MFMA16(ah[mi], bl[ni], acc[mi][ni], 0, 0, 0);
            }
        __syncthreads();
    }
}

// ---------------------------------------------------------------------------
// QKV projection (MFMA). Q: *0.125 hi/lo; K: hi only; V: bf16 transposed.
// ---------------------------------------------------------------------------
__global__ __launch_bounds__(256, 2) void qkv_mfma_kernel(
    const unsigned short* __restrict__ xhi, const unsigned short* __restrict__ xlo,
    const unsigned short* __restrict__ Wthi, const unsigned short* __restrict__ Wtlo,
    const float* __restrict__ bq, const float* __restrict__ bk, const float* __restrict__ bv,
    unsigned short* __restrict__ Qhi, unsigned short* __restrict__ Qlo,
    unsigned short* __restrict__ Khi,
    unsigned short* __restrict__ Vt)
{
    __shared__ __align__(16) char smem[33280];
    const int t    = threadIdx.x;
    const int lane = t & 63;
    const int wid  = t >> 6;
    const int quad = lane >> 4, l16 = lane & 15;
    const int wm   = wid >> 1,  wn  = wid & 1;

    const int row0 = blockIdx.x * 128;
    const int yb   = blockIdx.y;
    const int mtx  = yb >> 2;
    const int col0 = (yb & 3) * 128;

    f32x4 acc[4][4];
    #pragma unroll
    for (int i = 0; i < 4; ++i)
        #pragma unroll
        for (int j = 0; j < 4; ++j) acc[i][j] = (f32x4){0.f, 0.f, 0.f, 0.f};

    const size_t wslot = (size_t)mtx * DMODEL * DMODEL;
    gemm_k_loop(xhi + (size_t)row0 * DMODEL, xlo + (size_t)row0 * DMODEL,
                Wthi + wslot + (size_t)col0 * DMODEL, Wtlo + wslot + (size_t)col0 * DMODEL,
                smem, acc);

    const float* bias = (mtx == 0) ? bq : (mtx == 1) ? bk : bv;
    float bcol[4];
    #pragma unroll
    for (int ni = 0; ni < 4; ++ni) bcol[ni] = bias[col0 + wn * 64 + ni * 16 + l16];
    const int h = (col0 + wn * 64) >> 6;

    if (mtx < 2) {
        const float scale = (mtx == 0) ? 0.125f : 1.0f;
        unsigned short* hig = (mtx == 0) ? Qhi : Khi;
        #pragma unroll
        for (int mi = 0; mi < 4; ++mi) {
            #pragma unroll
            for (int reg = 0; reg < 4; ++reg) {
                const int r = row0 + wm * 64 + mi * 16 + quad * 4 + reg;
                const int b = r >> 11, n = r & 2047;
                const size_t rowbase = ((size_t)(b * NH + h) * NSEQ + n) * HDIM;
                #pragma unroll
                for (int ni = 0; ni < 4; ++ni) {
                    float f = (acc[mi][ni][reg] + bcol[ni]) * scale;
                    unsigned short hi = f2bf(f);
                    hig[rowbase + ni * 16 + l16] = hi;
                    if (mtx == 0)
                        Qlo[rowbase + ni * 16 + l16] = f2bf(f - bf2f(hi));
                }
            }
        }
    } else {
        // V: bias + bf16, transpose 64x64 per wave through LDS (stride 65)
        unsigned short* vt = (unsigned short*)smem + (size_t)wid * 64 * 65;
        #pragma unroll
        for (int mi = 0; mi < 4; ++mi)
            #pragma unroll
            for (int ni = 0; ni < 4; ++ni)
                #pragma unroll
                for (int reg = 0; reg < 4; ++reg)
                    vt[(mi * 16 + quad * 4 + reg) * 65 + ni * 16 + l16] =
                        f2bf(acc[mi][ni][reg] + bcol[ni]);
        const int b   = row0 >> 11;
        const int n0g = (row0 & 2047) + wm * 64;
        const int bh  = b * NH + h;
        unsigned short* gdst = Vt + ((size_t)bh * HDIM + lane) * NSEQ + n0g;
        #pragma unroll
        for (int nb = 0; nb < 8; ++nb) {
            unsigned short v[8];
            #pragma unroll
            for (int j = 0; j < 8; ++j) v[j] = vt[(nb * 8 + j) * 65 + lane];
            uint4 u;
            u.x = (unsigned)v[0] | ((unsigned)v[1] << 16);
            u.y = (unsigned)v[2] | ((unsigned)v[3] << 16);
            u.z = (unsigned)v[4] | ((unsigned)v[5] << 16);
            u.w = (unsigned)v[6] | ((unsigned)v[7] << 16);
            *(uint4*)(gdst + nb * 8) = u;
        }
    }
}

// ---------------------------------------------------------------------------
// Output projection (MFMA): ctx(hi/lo) @ Wo^T + bo -> out fp32 [B,N,D]
// ---------------------------------------------------------------------------
__global__ __launch_bounds__(256, 2) void out_mfma_kernel(
    const unsigned short* __restrict__ chi, const unsigned short* __restrict__ clo,
    const unsigned short* __restrict__ Wthi, const unsigned short* __restrict__ Wtlo,
    const float* __restrict__ bo, float* __restrict__ out)
{
    __shared__ __align__(16) char smem[32768];
    const int t    = threadIdx.x;
    const int lane = t & 63;
    const int wid  = t >> 6;
    const int quad = lane >> 4, l16 = lane & 15;
    const int wm   = wid >> 1,  wn  = wid & 1;

    const int row0 = blockIdx.x * 128;
    const int col0 = blockIdx.y * 128;

    f32x4 acc[4][4];
    #pragma unroll
    for (int i = 0; i < 4; ++i)
        #pragma unroll
        for (int j = 0; j < 4; ++j) acc[i][j] = (f32x4){0.f, 0.f, 0.f, 0.f};

    const size_t wslot = (size_t)3 * DMODEL * DMODEL;   // Wo
    gemm_k_loop(chi + (size_t)row0 * DMODEL, clo + (size_t)row0 * DMODEL,
                Wthi + wslot + (size_t)col0 * DMODEL, Wtlo + wslot + (size_t)col0 * DMODEL,
                smem, acc);

    float bcol[4];
    #pragma unroll
    for (int ni = 0; ni < 4; ++ni) bcol[ni] = bo[col0 + wn * 64 + ni * 16 + l16];
    #pragma unroll
    for (int mi = 0; mi < 4; ++mi)
        #pragma unroll
        for (int reg = 0; reg < 4; ++reg) {
            const int r = row0 + wm * 64 + mi * 16 + quad * 4 + reg;
            float* orow = out + (size_t)r * DMODEL + col0 + wn * 64 + l16;
            #pragma unroll
            for (int ni = 0; ni < 4; ++ni)
                orow[ni * 16] = acc[mi][ni][reg] + bcol[ni];
        }
}

// ---------------------------------------------------------------------------
// Barrier-free MFMA flash attention.
// Block = 4 waves x 32 q-rows = 128 q-rows per (head,batch); 512 blocks.
// K and V fragments are loaded DIRECTLY from global (L1/L2-served; K/V per
// head is 256 KB each -> L2-resident). LDS holds only the per-wave P
// C-layout->A-layout transpose slot (wave-ordered, no __syncthreads).
// Each wave processes 2 q-subtiles (s=0,1) sharing every K/V fragment.
// l-sum via constant ones B-frag; mask via 64-bit bitmask AND; p = exp(s).
// ---------------------------------------------------------------------------
__global__ __launch_bounds__(256) void attn_kernel(
    const unsigned short* __restrict__ Qhi, const unsigned short* __restrict__ Qlo,
    const unsigned short* __restrict__ Khi,
    const unsigned short* __restrict__ Vt,
    const unsigned long long* __restrict__ Mb,
    unsigned short* __restrict__ chi, unsigned short* __restrict__ clo)
{
    __shared__ __align__(16) unsigned short PS[4][32 * STR];   // 18.4 KB

    const int t    = threadIdx.x;
    const int wq   = t >> 6;        // wave 0..3
    const int lane = t & 63;
    const int quad = lane >> 4;
    const int l16  = lane & 15;
    const int q0   = blockIdx.x * 128;
    const int h    = blockIdx.y;
    const int b    = blockIdx.z;
    const int bh   = b * NH + h;
    const int qa   = q0 + wq * 32;  // this wave's 32 q-rows

    // Q fragments for both subtiles (A-operand), *0.125 applied at projection
    short8 qh[2][2], ql[2][2];
    #pragma unroll
    for (int s = 0; s < 2; ++s) {
        const int qrow = qa + s * 16 + l16;
        const unsigned short* gq = Qhi + ((size_t)bh * NSEQ + qrow) * HDIM + quad * 8;
        const unsigned short* gl = Qlo + ((size_t)bh * NSEQ + qrow) * HDIM + quad * 8;
        qh[s][0] = *(const short8*)gq;  qh[s][1] = *(const short8*)(gq + 32);
        ql[s][0] = *(const short8*)gl;  ql[s][1] = *(const short8*)(gl + 32);
    }
    const unsigned long long* mrow0 = Mb + (qa + l16);
    const unsigned long long* mrow1 = Mb + (qa + 16 + l16);

    short8 onesf;
    #pragma unroll
    for (int i = 0; i < 8; ++i) onesf[i] = (short)0x3F80;   // bf16 1.0

    f32x4 O[2][5];
    #pragma unroll
    for (int s = 0; s < 2; ++s)
        #pragma unroll
        for (int ng = 0; ng < 5; ++ng) O[s][ng] = (f32x4){0.f, 0.f, 0.f, 0.f};

    const unsigned short* gk = Khi + (size_t)bh * NSEQ * HDIM;
    const unsigned short* gv = Vt  + (size_t)bh * HDIM * NSEQ;
    unsigned short* ps = &PS[wq][0];

    for (int kt = 0; kt < NSEQ / 64; ++kt) {
        const int k0 = kt * 64;

        // ---- K fragments straight from global (8 x b128) ----
        short8 kh[4][2];
        #pragma unroll
        for (int cg = 0; cg < 4; ++cg) {
            const unsigned short* gr = gk + (size_t)(k0 + cg * 16 + l16) * HDIM + quad * 8;
            kh[cg][0] = *(const short8*)gr;
            kh[cg][1] = *(const short8*)(gr + 32);
        }
        const unsigned long long mwa = mrow0[(size_t)kt * NSEQ];
        const unsigned long long mwb = mrow1[(size_t)kt * NSEQ];

        // ---- S = (Qhi+Qlo) K^T ; p = exp(s) -> PS (bf16 truncate, C-layout) ----
        #pragma unroll
        for (int s = 0; s < 2; ++s)
            #pragma unroll
            for (int cg = 0; cg < 4; ++cg) {
                f32x4 sS = (f32x4){0.f, 0.f, 0.f, 0.f};
                sS = MFMA16(qh[s][0], kh[cg][0], sS, 0, 0, 0);
                sS = MFMA16(ql[s][0], kh[cg][0], sS, 0, 0, 0);
                sS = MFMA16(qh[s][1], kh[cg][1], sS, 0, 0, 0);
                sS = MFMA16(ql[s][1], kh[cg][1], sS, 0, 0, 0);
                #pragma unroll
                for (int r4 = 0; r4 < 4; ++r4) {
                    float p = __expf(sS[r4]);
                    ps[(s * 16 + quad * 4 + r4) * STR + cg * 16 + l16] =
                        (unsigned short)(__float_as_uint(p) >> 16);
                }
            }

        // ---- V fragments straight from global (8 x b128), in flight early ----
        short8 vf[4][2];
        #pragma unroll
        for (int ng = 0; ng < 4; ++ng) {
            const unsigned short* vr = gv + (size_t)(ng * 16 + l16) * NSEQ + k0 + quad * 8;
            vf[ng][0] = *(const short8*)vr;
            vf[ng][1] = *(const short8*)(vr + 32);
        }

        // ---- P back in A-layout, apply bitmask ----
        short8 p[2][2];
        p[0][0] = *(const short8*)&ps[l16 * STR + quad * 8];
        p[0][1] = *(const short8*)&ps[l16 * STR + 32 + quad * 8];
        p[1][0] = *(const short8*)&ps[(16 + l16) * STR + quad * 8];
        p[1][1] = *(const short8*)&ps[(16 + l16) * STR + 32 + quad * 8];
        p[0][0] = andmask8(p[0][0], ((unsigned)mwa         >> (quad * 8)) & 0xFFu);
        p[0][1] = andmask8(p[0][1], ((unsigned)(mwa >> 32) >> (quad * 8)) & 0xFFu);
        p[1][0] = andmask8(p[1][0], ((unsigned)mwb         >> (quad * 8)) & 0xFFu);
        p[1][1] = andmask8(p[1][1], ((unsigned)(mwb >> 32) >> (quad * 8)) & 0xFFu);

        // ---- O += P @ V ; l += P @ ones ----
        #pragma unroll
        for (int ng = 0; ng < 4; ++ng) {
            O[0][ng] = MFMA16(p[0][0], vf[ng][0], O[0][ng], 0, 0, 0);
            O[0][ng] = MFMA16(p[0][1], vf[ng][1], O[0][ng], 0, 0, 0);
            O[1][ng] = MFMA16(p[1][0], vf[ng][0], O[1][ng], 0, 0, 0);
            O[1][ng] = MFMA16(p[1][1], vf[ng][1], O[1][ng], 0, 0, 0);
        }
        O[0][4] = MFMA16(p[0][0], onesf, O[0][4], 0, 0, 0);
        O[0][4] = MFMA16(p[0][1], onesf, O[0][4], 0, 0, 0);
        O[1][4] = MFMA16(p[1][0], onesf, O[1][4], 0, 0, 0);
        O[1][4] = MFMA16(p[1][1], onesf, O[1][4], 0, 0, 0);
    }

    // ---- normalize by l (= O[s][4], same value in every column), write ctx ----
    #pragma unroll
    for (int s = 0; s < 2; ++s)
        #pragma unroll
        for (int r4 = 0; r4 < 4; ++r4) {
            const float inv = 1.0f / O[s][4][r4];
            const int qrow = qa + s * 16 + quad * 4 + r4;
            const size_t base = ((size_t)b * NSEQ + qrow) * DMODEL + h * HDIM + l16;
            #pragma unroll
            for (int ng = 0; ng < 4; ++ng) {
                float f = O[s][ng][r4] * inv;
                unsigned short hi = f2bf(f);
                unsigned short lo = f2bf(f - bf2f(hi));
                chi[base + ng * 16] = hi;
                clo[base + ng * 16] = lo;
            }
        }
}

// ---------------------------------------------------------------------------
extern "C" void kernel_launch(void* const* d_in, const int* in_sizes, int n_in,
                              void* d_out, int out_size, void* d_ws, size_t ws_size,
                              hipStream_t stream) {
    const float* x   = (const float*)d_in[0];
    const float* adj = (const float*)d_in[1];
    const float* Wq  = (const float*)d_in[2];
    const float* bq  = (const float*)d_in[3];
    const float* Wk  = (const float*)d_in[4];
    const float* bk  = (const float*)d_in[5];
    const float* Wv  = (const float*)d_in[6];
    const float* bv  = (const float*)d_in[7];
    const float* Wo  = (const float*)d_in[8];
    const float* bo  = (const float*)d_in[9];
    float* out = (float*)d_out;

    const size_t elems = (size_t)NB * NSEQ * DMODEL;   // 4,194,304
    unsigned short* Qhi  = (unsigned short*)d_ws;
    unsigned short* Qlo  = Qhi + elems;
    unsigned short* Khi  = Qlo + elems;
    unsigned short* Klo  = Khi + elems;                // unused (layout stability)
    unsigned short* Vt   = Klo + elems;
    unsigned long long* Mbits = (unsigned long long*)(Vt + elems);  // 512 KB slot
    unsigned short* xhi  = Vt + 2 * elems;             // after the mask slot
    unsigned short* xlo  = xhi + elems;
    unsigned short* Wthi = xlo + elems;                // 4 * 512*512
    unsigned short* Wtlo = Wthi + 4 * (size_t)DMODEL * DMODEL;
    // ctx aliases xhi/xlo (dead after qkv_mfma_kernel)
    unsigned short* chi = xhi;
    unsigned short* clo = xlo;

    mask_kernel   <<<dim3(16384), dim3(256), 0, stream>>>(adj, Mbits);
    split_x_kernel<<<dim3(4096), dim3(256), 0, stream>>>(x, xhi, xlo);
    split_wt_kernel<<<dim3(16, 16, 4), dim3(256), 0, stream>>>(Wq, Wk, Wv, Wo, Wthi, Wtlo);
    qkv_mfma_kernel<<<dim3(64, 12), dim3(256), 0, stream>>>(
        xhi, xlo, Wthi, Wtlo, bq, bk, bv, Qhi, Qlo, Khi, Vt);
    attn_kernel<<<dim3(NSEQ / 128, NH, NB), dim3(256), 0, stream>>>(
        Qhi, Qlo, Khi, Vt, Mbits, chi, clo);
    out_mfma_kernel<<<dim3(64, 4), dim3(256), 0, stream>>>(
        chi, clo, Wthi, Wtlo, bo, out);
}

// Round 7
// 242.069 us; speedup vs baseline: 1.1722x; 1.1722x over previous
//
#include <hip/hip_runtime.h>
#include <math.h>

#define NB    4
#define NSEQ  2048
#define DMODEL 512
#define NH    8
#define HDIM  64
#define STR   72   // attn LDS tile row stride (bf16 units): 144B rows, 16B-aligned

typedef __attribute__((ext_vector_type(8))) short short8;
typedef __attribute__((ext_vector_type(4))) float f32x4;
#define MFMA16 __builtin_amdgcn_mfma_f32_16x16x32_bf16

__device__ __forceinline__ unsigned short f2bf(float f) {
    union { float f; unsigned int u; } v; v.f = f;
    unsigned int u = v.u;
    unsigned int r = (u + 0x7FFFu + ((u >> 16) & 1u)) >> 16;   // RNE
    return (unsigned short)r;
}
__device__ __forceinline__ float bf2f(unsigned short h) {
    union { unsigned int u; float f; } v; v.u = ((unsigned int)h) << 16;
    return v.f;
}
// AND a P-fragment (8 bf16, keys j=0..7) with 8 adjacency bits
__device__ __forceinline__ short8 andmask8(short8 p, unsigned bits) {
    union { short8 s; uint4 u; } x; x.s = p;
    x.u.x &= ((bits &   1u) ? 0xFFFFu : 0u) | ((bits &   2u) ? 0xFFFF0000u : 0u);
    x.u.y &= ((bits &   4u) ? 0xFFFFu : 0u) | ((bits &   8u) ? 0xFFFF0000u : 0u);
    x.u.z &= ((bits &  16u) ? 0xFFFFu : 0u) | ((bits &  32u) ? 0xFFFF0000u : 0u);
    x.u.w &= ((bits &  64u) ? 0xFFFFu : 0u) | ((bits & 128u) ? 0xFFFF0000u : 0u);
    return x.s;
}
__device__ __forceinline__ void async16(void* lds, const void* g) {
    __builtin_amdgcn_global_load_lds(
        (const __attribute__((address_space(1))) unsigned int*)g,
        (__attribute__((address_space(3))) unsigned int*)lds, 16, 0, 0);
}

// ---------------------------------------------------------------------------
// Mask precompute: Mb[kt*2048 + q] = 64-bit word, bit i = adj[q][kt*64+i] > 0.5
// ---------------------------------------------------------------------------
__global__ __launch_bounds__(256) void mask_kernel(const float* __restrict__ adj,
                                                   unsigned long long* __restrict__ Mb) {
    const int w    = blockIdx.x * 4 + (threadIdx.x >> 6);   // global wave id
    const int lane = threadIdx.x & 63;
    const int q  = w >> 5;          // 0..2047
    const int kt = w & 31;          // 0..31
    float a = adj[(size_t)q * NSEQ + kt * 64 + lane];
    unsigned long long m = __ballot(a > 0.5f);
    if (lane == 0) Mb[(size_t)kt * NSEQ + q] = m;
}

// ---------------------------------------------------------------------------
// Split x (fp32) -> xhi, xlo bf16
// ---------------------------------------------------------------------------
__global__ __launch_bounds__(256) void split_x_kernel(const float* __restrict__ x,
                                                      unsigned short* __restrict__ xhi,
                                                      unsigned short* __restrict__ xlo) {
    int gid = blockIdx.x * 256 + threadIdx.x;
    float4 a = ((const float4*)x)[gid];
    float f[4] = {a.x, a.y, a.z, a.w};
    ushort4 h4, l4;
    unsigned short hs[4], ls[4];
    #pragma unroll
    for (int j = 0; j < 4; ++j) {
        hs[j] = f2bf(f[j]);
        ls[j] = f2bf(f[j] - bf2f(hs[j]));
    }
    h4.x = hs[0]; h4.y = hs[1]; h4.z = hs[2]; h4.w = hs[3];
    l4.x = ls[0]; l4.y = ls[1]; l4.z = ls[2]; l4.w = ls[3];
    ((ushort4*)xhi)[gid] = h4;
    ((ushort4*)xlo)[gid] = l4;
}

// ---------------------------------------------------------------------------
// Transpose + split weights: W[k][n] fp32 -> Wt_hi/Wt_lo [mat][n][k] bf16.
// ---------------------------------------------------------------------------
__global__ __launch_bounds__(256) void split_wt_kernel(
    const float* __restrict__ Wq, const float* __restrict__ Wk,
    const float* __restrict__ Wv, const float* __restrict__ Wo,
    unsigned short* __restrict__ Wthi, unsigned short* __restrict__ Wtlo)
{
    __shared__ float tile[32][33];
    const int m = blockIdx.z;
    const float* W = (m == 0) ? Wq : (m == 1) ? Wk : (m == 2) ? Wv : Wo;
    const int k0 = blockIdx.x * 32, n0 = blockIdx.y * 32;
    const int tx = threadIdx.x & 31, ty = threadIdx.x >> 5;
    #pragma unroll
    for (int i = 0; i < 4; ++i)
        tile[ty * 4 + i][tx] = W[(size_t)(k0 + ty * 4 + i) * DMODEL + n0 + tx];
    __syncthreads();
    const size_t base = ((size_t)m * DMODEL) * DMODEL;
    #pragma unroll
    for (int i = 0; i < 4; ++i) {
        float f = tile[tx][ty * 4 + i];
        unsigned short hi = f2bf(f);
        unsigned short lo = f2bf(f - bf2f(hi));
        size_t idx = base + (size_t)(n0 + ty * 4 + i) * DMODEL + k0 + tx;
        Wthi[idx] = hi;
        Wtlo[idx] = lo;
    }
}

// ---------------------------------------------------------------------------
// Shared MFMA GEMM K-loop (hi/lo 3-term), 128x128 tile, BK=32, XOR-swizzled LDS.
// ---------------------------------------------------------------------------
__device__ __forceinline__ void gemm_k_loop(
    const unsigned short* __restrict__ Ah, const unsigned short* __restrict__ Al,
    const unsigned short* __restrict__ Bh, const unsigned short* __restrict__ Bl,
    char* smem, f32x4 acc[4][4])
{
    const int t    = threadIdx.x;
    const int lane = t & 63;
    const int wid  = t >> 6;
    const int quad = lane >> 4, l16 = lane & 15;
    const int wm   = wid >> 1,  wn  = wid & 1;

    unsigned short* As_h = (unsigned short*)(smem);
    unsigned short* As_l = (unsigned short*)(smem + 8192);
    unsigned short* Bs_h = (unsigned short*)(smem + 16384);
    unsigned short* Bs_l = (unsigned short*)(smem + 24576);

    const int ci0 = t, ci1 = 256 + t;
    const int r0 = ci0 >> 2, r1 = ci1 >> 2;
    const int c0 = (ci0 & 3) ^ ((r0 >> 1) & 3);
    const int c1 = (ci1 & 3) ^ ((r1 >> 1) & 3);
    const char* gAh = (const char*)Ah;  const char* gAl = (const char*)Al;
    const char* gBh = (const char*)Bh;  const char* gBl = (const char*)Bl;
    const int ca = quad ^ ((l16 >> 1) & 3);

    for (int k0 = 0; k0 < DMODEL; k0 += 32) {
        const int kb = k0 * 2;
        async16(As_h + ci0 * 8, gAh + r0 * 1024 + kb + c0 * 16);
        async16(As_h + ci1 * 8, gAh + r1 * 1024 + kb + c1 * 16);
        async16(As_l + ci0 * 8, gAl + r0 * 1024 + kb + c0 * 16);
        async16(As_l + ci1 * 8, gAl + r1 * 1024 + kb + c1 * 16);
        async16(Bs_h + ci0 * 8, gBh + r0 * 1024 + kb + c0 * 16);
        async16(Bs_h + ci1 * 8, gBh + r1 * 1024 + kb + c1 * 16);
        async16(Bs_l + ci0 * 8, gBl + r0 * 1024 + kb + c0 * 16);
        async16(Bs_l + ci1 * 8, gBl + r1 * 1024 + kb + c1 * 16);
        __syncthreads();

        short8 ah[4], al[4], bh[4], bl[4];
        #pragma unroll
        for (int i = 0; i < 4; ++i) {
            const int Ra = wm * 64 + i * 16 + l16;
            ah[i] = *(const short8*)(As_h + Ra * 32 + ca * 8);
            al[i] = *(const short8*)(As_l + Ra * 32 + ca * 8);
            const int Rb = wn * 64 + i * 16 + l16;
            bh[i] = *(const short8*)(Bs_h + Rb * 32 + ca * 8);
            bl[i] = *(const short8*)(Bs_l + Rb * 32 + ca * 8);
        }
        #pragma unroll
        for (int mi = 0; mi < 4; ++mi)
            #pragma unroll
            for (int ni = 0; ni < 4; ++ni) {
                acc[mi][ni] = MFMA16(ah[mi], bh[ni], acc[mi][ni], 0, 0, 0);
                acc[mi][ni] = MFMA16(al[mi], bh[ni], acc[mi][ni], 0, 0, 0);
                acc[mi][ni] = MFMA16(ah[mi], bl[ni], acc[mi][ni], 0, 0, 0);
            }
        __syncthreads();
    }
}

// ---------------------------------------------------------------------------
// QKV projection (MFMA). Q: *0.125 hi/lo; K: hi only; V: bf16 transposed.
// ---------------------------------------------------------------------------
__global__ __launch_bounds__(256, 2) void qkv_mfma_kernel(
    const unsigned short* __restrict__ xhi, const unsigned short* __restrict__ xlo,
    const unsigned short* __restrict__ Wthi, const unsigned short* __restrict__ Wtlo,
    const float* __restrict__ bq, const float* __restrict__ bk, const float* __restrict__ bv,
    unsigned short* __restrict__ Qhi, unsigned short* __restrict__ Qlo,
    unsigned short* __restrict__ Khi,
    unsigned short* __restrict__ Vt)
{
    __shared__ __align__(16) char smem[33280];
    const int t    = threadIdx.x;
    const int lane = t & 63;
    const int wid  = t >> 6;
    const int quad = lane >> 4, l16 = lane & 15;
    const int wm   = wid >> 1,  wn  = wid & 1;

    const int row0 = blockIdx.x * 128;
    const int yb   = blockIdx.y;
    const int mtx  = yb >> 2;
    const int col0 = (yb & 3) * 128;

    f32x4 acc[4][4];
    #pragma unroll
    for (int i = 0; i < 4; ++i)
        #pragma unroll
        for (int j = 0; j < 4; ++j) acc[i][j] = (f32x4){0.f, 0.f, 0.f, 0.f};

    const size_t wslot = (size_t)mtx * DMODEL * DMODEL;
    gemm_k_loop(xhi + (size_t)row0 * DMODEL, xlo + (size_t)row0 * DMODEL,
                Wthi + wslot + (size_t)col0 * DMODEL, Wtlo + wslot + (size_t)col0 * DMODEL,
                smem, acc);

    const float* bias = (mtx == 0) ? bq : (mtx == 1) ? bk : bv;
    float bcol[4];
    #pragma unroll
    for (int ni = 0; ni < 4; ++ni) bcol[ni] = bias[col0 + wn * 64 + ni * 16 + l16];
    const int h = (col0 + wn * 64) >> 6;

    if (mtx < 2) {
        const float scale = (mtx == 0) ? 0.125f : 1.0f;
        unsigned short* hig = (mtx == 0) ? Qhi : Khi;
        #pragma unroll
        for (int mi = 0; mi < 4; ++mi) {
            #pragma unroll
            for (int reg = 0; reg < 4; ++reg) {
                const int r = row0 + wm * 64 + mi * 16 + quad * 4 + reg;
                const int b = r >> 11, n = r & 2047;
                const size_t rowbase = ((size_t)(b * NH + h) * NSEQ + n) * HDIM;
                #pragma unroll
                for (int ni = 0; ni < 4; ++ni) {
                    float f = (acc[mi][ni][reg] + bcol[ni]) * scale;
                    unsigned short hi = f2bf(f);
                    hig[rowbase + ni * 16 + l16] = hi;
                    if (mtx == 0)
                        Qlo[rowbase + ni * 16 + l16] = f2bf(f - bf2f(hi));
                }
            }
        }
    } else {
        // V: bias + bf16, transpose 64x64 per wave through LDS (stride 65)
        unsigned short* vt = (unsigned short*)smem + (size_t)wid * 64 * 65;
        #pragma unroll
        for (int mi = 0; mi < 4; ++mi)
            #pragma unroll
            for (int ni = 0; ni < 4; ++ni)
                #pragma unroll
                for (int reg = 0; reg < 4; ++reg)
                    vt[(mi * 16 + quad * 4 + reg) * 65 + ni * 16 + l16] =
                        f2bf(acc[mi][ni][reg] + bcol[ni]);
        const int b   = row0 >> 11;
        const int n0g = (row0 & 2047) + wm * 64;
        const int bh  = b * NH + h;
        unsigned short* gdst = Vt + ((size_t)bh * HDIM + lane) * NSEQ + n0g;
        #pragma unroll
        for (int nb = 0; nb < 8; ++nb) {
            unsigned short v[8];
            #pragma unroll
            for (int j = 0; j < 8; ++j) v[j] = vt[(nb * 8 + j) * 65 + lane];
            uint4 u;
            u.x = (unsigned)v[0] | ((unsigned)v[1] << 16);
            u.y = (unsigned)v[2] | ((unsigned)v[3] << 16);
            u.z = (unsigned)v[4] | ((unsigned)v[5] << 16);
            u.w = (unsigned)v[6] | ((unsigned)v[7] << 16);
            *(uint4*)(gdst + nb * 8) = u;
        }
    }
}

// ---------------------------------------------------------------------------
// Output projection (MFMA): ctx(hi/lo) @ Wo^T + bo -> out fp32 [B,N,D]
// ---------------------------------------------------------------------------
__global__ __launch_bounds__(256, 2) void out_mfma_kernel(
    const unsigned short* __restrict__ chi, const unsigned short* __restrict__ clo,
    const unsigned short* __restrict__ Wthi, const unsigned short* __restrict__ Wtlo,
    const float* __restrict__ bo, float* __restrict__ out)
{
    __shared__ __align__(16) char smem[32768];
    const int t    = threadIdx.x;
    const int lane = t & 63;
    const int wid  = t >> 6;
    const int quad = lane >> 4, l16 = lane & 15;
    const int wm   = wid >> 1,  wn  = wid & 1;

    const int row0 = blockIdx.x * 128;
    const int col0 = blockIdx.y * 128;

    f32x4 acc[4][4];
    #pragma unroll
    for (int i = 0; i < 4; ++i)
        #pragma unroll
        for (int j = 0; j < 4; ++j) acc[i][j] = (f32x4){0.f, 0.f, 0.f, 0.f};

    const size_t wslot = (size_t)3 * DMODEL * DMODEL;   // Wo
    gemm_k_loop(chi + (size_t)row0 * DMODEL, clo + (size_t)row0 * DMODEL,
                Wthi + wslot + (size_t)col0 * DMODEL, Wtlo + wslot + (size_t)col0 * DMODEL,
                smem, acc);

    float bcol[4];
    #pragma unroll
    for (int ni = 0; ni < 4; ++ni) bcol[ni] = bo[col0 + wn * 64 + ni * 16 + l16];
    #pragma unroll
    for (int mi = 0; mi < 4; ++mi)
        #pragma unroll
        for (int reg = 0; reg < 4; ++reg) {
            const int r = row0 + wm * 64 + mi * 16 + quad * 4 + reg;
            float* orow = out + (size_t)r * DMODEL + col0 + wn * 64 + l16;
            #pragma unroll
            for (int ni = 0; ni < 4; ++ni)
                orow[ni * 16] = acc[mi][ni][reg] + bcol[ni];
        }
}

// ---------------------------------------------------------------------------
// MFMA flash attention. Block = 4 waves x 32 q-rows = 128 q-rows, 256 threads,
// 512 blocks (2 blocks/CU -> barrier alternation hides staging latency).
// K/V tiles staged in LDS (round-5 structure); each wave's 2 q-subtiles share
// every K/V fragment read (round-6's traffic cut, without its latency exposure).
// Mask: 64-bit bitmask AND; l-sum via constant ones B-frag; p = exp(s).
// ---------------------------------------------------------------------------
__global__ __launch_bounds__(256) void attn_kernel(
    const unsigned short* __restrict__ Qhi, const unsigned short* __restrict__ Qlo,
    const unsigned short* __restrict__ Khi,
    const unsigned short* __restrict__ Vt,
    const unsigned long long* __restrict__ Mb,
    unsigned short* __restrict__ chi, unsigned short* __restrict__ clo)
{
    __shared__ __align__(16) unsigned short KS[64 * STR];      // 9.2 KB
    __shared__ __align__(16) unsigned short VS[64 * STR];      // 9.2 KB
    __shared__ __align__(16) unsigned short PS[4][32 * STR];   // 18.4 KB

    const int t    = threadIdx.x;
    const int wq   = t >> 6;        // wave 0..3
    const int lane = t & 63;
    const int quad = lane >> 4;
    const int l16  = lane & 15;
    const int q0   = blockIdx.x * 128;
    const int h    = blockIdx.y;
    const int b    = blockIdx.z;
    const int bh   = b * NH + h;
    const int qa   = q0 + wq * 32;  // this wave's 32 q-rows

    // Q fragments for both subtiles (A-operand), *0.125 applied at projection
    short8 qh[2][2], ql[2][2];
    #pragma unroll
    for (int s = 0; s < 2; ++s) {
        const int qrow = qa + s * 16 + l16;
        const unsigned short* gq = Qhi + ((size_t)bh * NSEQ + qrow) * HDIM + quad * 8;
        const unsigned short* gl = Qlo + ((size_t)bh * NSEQ + qrow) * HDIM + quad * 8;
        qh[s][0] = *(const short8*)gq;  qh[s][1] = *(const short8*)(gq + 32);
        ql[s][0] = *(const short8*)gl;  ql[s][1] = *(const short8*)(gl + 32);
    }
    const unsigned long long* mrow0 = Mb + (qa + l16);
    const unsigned long long* mrow1 = Mb + (qa + 16 + l16);

    short8 onesf;
    #pragma unroll
    for (int i = 0; i < 8; ++i) onesf[i] = (short)0x3F80;   // bf16 1.0

    f32x4 O[2][5];
    #pragma unroll
    for (int s = 0; s < 2; ++s)
        #pragma unroll
        for (int ng = 0; ng < 5; ++ng) O[s][ng] = (f32x4){0.f, 0.f, 0.f, 0.f};

    const unsigned short* gk = Khi + (size_t)bh * NSEQ * HDIM;
    const unsigned short* gv = Vt  + (size_t)bh * HDIM * NSEQ;
    unsigned short* ps = &PS[wq][0];

    // staging assignments: 512 chunks (64 rows x 8 x 16B) per tile, 2/thread
    const int ci0 = t, ci1 = t + 256;
    const int sr0 = ci0 >> 3, sc0 = (ci0 & 7) * 8;
    const int sr1 = ci1 >> 3, sc1 = (ci1 & 7) * 8;

    for (int kt = 0; kt < NSEQ / 64; ++kt) {
        const int k0 = kt * 64;
        // ---- stage K, V tiles ----
        *(uint4*)&KS[sr0 * STR + sc0] = *(const uint4*)(gk + (size_t)(k0 + sr0) * HDIM + sc0);
        *(uint4*)&KS[sr1 * STR + sc1] = *(const uint4*)(gk + (size_t)(k0 + sr1) * HDIM + sc1);
        *(uint4*)&VS[sr0 * STR + sc0] = *(const uint4*)(gv + (size_t)sr0 * NSEQ + k0 + sc0);
        *(uint4*)&VS[sr1 * STR + sc1] = *(const uint4*)(gv + (size_t)sr1 * NSEQ + k0 + sc1);
        __syncthreads();

        const unsigned long long mwa = mrow0[(size_t)kt * NSEQ];
        const unsigned long long mwb = mrow1[(size_t)kt * NSEQ];

        // ---- K fragments from LDS (8 x b128, shared by both subtiles) ----
        short8 kh[4][2];
        #pragma unroll
        for (int cg = 0; cg < 4; ++cg) {
            kh[cg][0] = *(const short8*)&KS[(cg * 16 + l16) * STR + quad * 8];
            kh[cg][1] = *(const short8*)&KS[(cg * 16 + l16) * STR + 32 + quad * 8];
        }

        // ---- S = (Qhi+Qlo) K^T ; p = exp(s) -> PS (bf16 truncate, C-layout) ----
        #pragma unroll
        for (int s = 0; s < 2; ++s)
            #pragma unroll
            for (int cg = 0; cg < 4; ++cg) {
                f32x4 sS = (f32x4){0.f, 0.f, 0.f, 0.f};
                sS = MFMA16(qh[s][0], kh[cg][0], sS, 0, 0, 0);
                sS = MFMA16(ql[s][0], kh[cg][0], sS, 0, 0, 0);
                sS = MFMA16(qh[s][1], kh[cg][1], sS, 0, 0, 0);
                sS = MFMA16(ql[s][1], kh[cg][1], sS, 0, 0, 0);
                #pragma unroll
                for (int r4 = 0; r4 < 4; ++r4) {
                    float p = __expf(sS[r4]);
                    ps[(s * 16 + quad * 4 + r4) * STR + cg * 16 + l16] =
                        (unsigned short)(__float_as_uint(p) >> 16);
                }
            }

        // ---- V fragments from LDS (8 x b128, shared by both subtiles) ----
        short8 vf[4][2];
        #pragma unroll
        for (int ng = 0; ng < 4; ++ng) {
            vf[ng][0] = *(const short8*)&VS[(ng * 16 + l16) * STR + quad * 8];
            vf[ng][1] = *(const short8*)&VS[(ng * 16 + l16) * STR + 32 + quad * 8];
        }

        // ---- P back in A-layout, apply bitmask ----
        short8 p[2][2];
        p[0][0] = *(const short8*)&ps[l16 * STR + quad * 8];
        p[0][1] = *(const short8*)&ps[l16 * STR + 32 + quad * 8];
        p[1][0] = *(const short8*)&ps[(16 + l16) * STR + quad * 8];
        p[1][1] = *(const short8*)&ps[(16 + l16) * STR + 32 + quad * 8];
        p[0][0] = andmask8(p[0][0], ((unsigned)mwa         >> (quad * 8)) & 0xFFu);
        p[0][1] = andmask8(p[0][1], ((unsigned)(mwa >> 32) >> (quad * 8)) & 0xFFu);
        p[1][0] = andmask8(p[1][0], ((unsigned)mwb         >> (quad * 8)) & 0xFFu);
        p[1][1] = andmask8(p[1][1], ((unsigned)(mwb >> 32) >> (quad * 8)) & 0xFFu);

        // ---- O += P @ V ; l += P @ ones ----
        #pragma unroll
        for (int ng = 0; ng < 4; ++ng) {
            O[0][ng] = MFMA16(p[0][0], vf[ng][0], O[0][ng], 0, 0, 0);
            O[0][ng] = MFMA16(p[0][1], vf[ng][1], O[0][ng], 0, 0, 0);
            O[1][ng] = MFMA16(p[1][0], vf[ng][0], O[1][ng], 0, 0, 0);
            O[1][ng] = MFMA16(p[1][1], vf[ng][1], O[1][ng], 0, 0, 0);
        }
        O[0][4] = MFMA16(p[0][0], onesf, O[0][4], 0, 0, 0);
        O[0][4] = MFMA16(p[0][1], onesf, O[0][4], 0, 0, 0);
        O[1][4] = MFMA16(p[1][0], onesf, O[1][4], 0, 0, 0);
        O[1][4] = MFMA16(p[1][1], onesf, O[1][4], 0, 0, 0);

        __syncthreads();   // protect KS/VS before next staging
    }

    // ---- normalize by l (= O[s][4], same value in every column), write ctx ----
    #pragma unroll
    for (int s = 0; s < 2; ++s)
        #pragma unroll
        for (int r4 = 0; r4 < 4; ++r4) {
            const float inv = 1.0f / O[s][4][r4];
            const int qrow = qa + s * 16 + quad * 4 + r4;
            const size_t base = ((size_t)b * NSEQ + qrow) * DMODEL + h * HDIM + l16;
            #pragma unroll
            for (int ng = 0; ng < 4; ++ng) {
                float f = O[s][ng][r4] * inv;
                unsigned short hi = f2bf(f);
                unsigned short lo = f2bf(f - bf2f(hi));
                chi[base + ng * 16] = hi;
                clo[base + ng * 16] = lo;
            }
        }
}

// ---------------------------------------------------------------------------
extern "C" void kernel_launch(void* const* d_in, const int* in_sizes, int n_in,
                              void* d_out, int out_size, void* d_ws, size_t ws_size,
                              hipStream_t stream) {
    const float* x   = (const float*)d_in[0];
    const float* adj = (const float*)d_in[1];
    const float* Wq  = (const float*)d_in[2];
    const float* bq  = (const float*)d_in[3];
    const float* Wk  = (const float*)d_in[4];
    const float* bk  = (const float*)d_in[5];
    const float* Wv  = (const float*)d_in[6];
    const float* bv  = (const float*)d_in[7];
    const float* Wo  = (const float*)d_in[8];
    const float* bo  = (const float*)d_in[9];
    float* out = (float*)d_out;

    const size_t elems = (size_t)NB * NSEQ * DMODEL;   // 4,194,304
    unsigned short* Qhi  = (unsigned short*)d_ws;
    unsigned short* Qlo  = Qhi + elems;
    unsigned short* Khi  = Qlo + elems;
    unsigned short* Klo  = Khi + elems;                // unused (layout stability)
    unsigned short* Vt   = Klo + elems;
    unsigned long long* Mbits = (unsigned long long*)(Vt + elems);  // 512 KB slot
    unsigned short* xhi  = Vt + 2 * elems;             // after the mask slot
    unsigned short* xlo  = xhi + elems;
    unsigned short* Wthi = xlo + elems;                // 4 * 512*512
    unsigned short* Wtlo = Wthi + 4 * (size_t)DMODEL * DMODEL;
    // ctx aliases xhi/xlo (dead after qkv_mfma_kernel)
    unsigned short* chi = xhi;
    unsigned short* clo = xlo;

    mask_kernel   <<<dim3(16384), dim3(256), 0, stream>>>(adj, Mbits);
    split_x_kernel<<<dim3(4096), dim3(256), 0, stream>>>(x, xhi, xlo);
    split_wt_kernel<<<dim3(16, 16, 4), dim3(256), 0, stream>>>(Wq, Wk, Wv, Wo, Wthi, Wtlo);
    qkv_mfma_kernel<<<dim3(64, 12), dim3(256), 0, stream>>>(
        xhi, xlo, Wthi, Wtlo, bq, bk, bv, Qhi, Qlo, Khi, Vt);
    attn_kernel<<<dim3(NSEQ / 128, NH, NB), dim3(256), 0, stream>>>(
        Qhi, Qlo, Khi, Vt, Mbits, chi, clo);
    out_mfma_kernel<<<dim3(64, 4), dim3(256), 0, stream>>>(
        chi, clo, Wthi, Wtlo, bo, out);
}